// Round 5
// baseline (303.254 us; speedup 1.0000x reference)
//
#include <hip/hip_runtime.h>
#include <hip/hip_bf16.h>
#include <math.h>

#define BB 8
#define CC 1024
#define TT 1024
#define HH 16
#define DD 64

typedef __attribute__((ext_vector_type(8))) short short8;
typedef __attribute__((ext_vector_type(4))) short short4_;
typedef __attribute__((ext_vector_type(4))) float f32x4;
typedef __attribute__((ext_vector_type(4))) int   i32x4;
typedef __attribute__((ext_vector_type(2))) unsigned long long u64x2;

#define QSCALE 0.18033688f   /* 0.125 * log2(e) */

__device__ __forceinline__ unsigned short f2bf(float f) {
    unsigned u = __builtin_bit_cast(unsigned, f);
    u += 0x7fffu + ((u >> 16) & 1u);
    return (unsigned short)(u >> 16);
}

__device__ __forceinline__ f32x4 mfma16(short8 a, short8 b, f32x4 c) {
    return __builtin_amdgcn_mfma_f32_16x16x32_bf16(a, b, c, 0, 0, 0);
}

// async global->LDS, 16B per lane; LDS dest = base + lane*16 (wave-uniform base)
__device__ __forceinline__ void async16(const void* g, void* l) {
    __builtin_amdgcn_global_load_lds(
        (const __attribute__((address_space(1))) unsigned int*)g,
        (__attribute__((address_space(3))) unsigned int*)l, 16, 0, 0);
}

// pack two f32 -> one dword of two bf16 (low = lo, high = hi)
__device__ __forceinline__ unsigned cvtpk(float lo, float hi) {
    unsigned r;
    asm("v_cvt_pk_bf16_f32 %0, %1, %2" : "=v"(r) : "v"(lo), "v"(hi));
    return r;
}

// ---------------------------------------------------------------------------
// Pre-pass A: cast the four weight matrices fp32 -> bf16 (concat at dst)
// ---------------------------------------------------------------------------
__global__ __launch_bounds__(256) void cast_w_kernel(
    const float* __restrict__ Wq, const float* __restrict__ Wk,
    const float* __restrict__ Wv, const float* __restrict__ Wo,
    unsigned short* __restrict__ dst)
{
    const int z = blockIdx.y;
    const float* W = (z == 0) ? Wq : (z == 1) ? Wk : (z == 2) ? Wv : Wo;
    unsigned short* d = dst + (size_t)z * CC * CC;
    int idx = blockIdx.x * 256 + threadIdx.x;
    float4 f = ((const float4*)W)[idx];
    short4_ s;
    s[0] = (short)f2bf(f.x); s[1] = (short)f2bf(f.y);
    s[2] = (short)f2bf(f.z); s[3] = (short)f2bf(f.w);
    ((short4_*)d)[idx] = s;
}

// ---------------------------------------------------------------------------
// Pre-pass B: transpose+cast both inputs  [b][c][t] fp32 -> [b][t][c] bf16
// grid (T/64, C/64, 2*B): z<B -> x, else ctx.
// ---------------------------------------------------------------------------
__global__ __launch_bounds__(256) void tcast2_kernel(
    const float* __restrict__ x, const float* __restrict__ ctx,
    unsigned short* __restrict__ xT, unsigned short* __restrict__ cTo)
{
    __shared__ float sT[64][65];
    const int tid = threadIdx.x;
    const int z = blockIdx.z;
    const float* in = (z < BB) ? x : ctx;
    unsigned short* out = (z < BB) ? xT : cTo;
    const int b = (z < BB) ? z : z - BB;
    const int tB = blockIdx.x * 64, cT = blockIdx.y * 64;

    const float* ib = in + ((size_t)b * CC + cT) * TT + tB;
    const int r = tid >> 2;
    #pragma unroll
    for (int j = 0; j < 4; j++) {
        int t4 = (tid & 3) * 4 + j * 16;
        float4 f = *(const float4*)(ib + (size_t)r * TT + t4);
        sT[r][t4 + 0] = f.x; sT[r][t4 + 1] = f.y;
        sT[r][t4 + 2] = f.z; sT[r][t4 + 3] = f.w;
    }
    __syncthreads();
    const int t_l = tid >> 2, cch = (tid & 3) * 16;
    short8 o0, o1;
    #pragma unroll
    for (int i = 0; i < 8; i++) {
        o0[i] = (short)f2bf(sT[cch + i][t_l]);
        o1[i] = (short)f2bf(sT[cch + 8 + i][t_l]);
    }
    unsigned short* dp = out + ((size_t)b * TT + tB + t_l) * CC + cT + cch;
    *(short8*)dp = o0;
    *(short8*)(dp + 8) = o1;
}

// single-input variant for the 72 MB fallback path
__global__ __launch_bounds__(256) void tcast_kernel(
    const float* __restrict__ in, unsigned short* __restrict__ out)
{
    __shared__ float sT[64][65];
    const int tid = threadIdx.x;
    const int tB = blockIdx.x * 64, cT = blockIdx.y * 64, b = blockIdx.z;

    const float* ib = in + ((size_t)b * CC + cT) * TT + tB;
    const int r = tid >> 2;
    #pragma unroll
    for (int j = 0; j < 4; j++) {
        int t4 = (tid & 3) * 4 + j * 16;
        float4 f = *(const float4*)(ib + (size_t)r * TT + t4);
        sT[r][t4 + 0] = f.x; sT[r][t4 + 1] = f.y;
        sT[r][t4 + 2] = f.z; sT[r][t4 + 3] = f.w;
    }
    __syncthreads();
    const int t_l = tid >> 2, cch = (tid & 3) * 16;
    short8 o0, o1;
    #pragma unroll
    for (int i = 0; i < 8; i++) {
        o0[i] = (short)f2bf(sT[cch + i][t_l]);
        o1[i] = (short)f2bf(sT[cch + 8 + i][t_l]);
    }
    unsigned short* dp = out + ((size_t)b * TT + tB + t_l) * CC + cT + cch;
    *(short8*)dp = o0;
    *(short8*)(dp + 8) = o1;
}

// ---------------------------------------------------------------------------
// QKV GEMM: 2-buffer single-barrier pipeline, x2-unrolled (compile-time
// buffer addresses). Per K-step: {vmcnt(0); s_barrier; stage(t+1 -> other
// buf); ds_read(cur); 16 MFMA; lgkmcnt(0)}. 32 barriers/block (was 64).
// LDS 36864 B -> 4 blocks/CU (VGPR-capped 4 waves/SIMD).
// Grid (zz, tTile, oTile): linear-id%8 = zz%8 -> all (t,o) blocks of one
// z-slice land on one XCD; weight+input panels fetched once per XCD.
// mode 0: zz -> (b=zz/3, w=zz%3).  mode 1: w=0, b=zz.  mode 2: w=1+(zz&1).
// Epilogue: bias + (w==0: fold QSCALE) + RoPE (rotation recurrence) + split.
// ---------------------------------------------------------------------------
__global__ __launch_bounds__(256) void qkv_gll_kernel(
    const unsigned short* __restrict__ xT, const unsigned short* __restrict__ cT,
    const unsigned short* __restrict__ Wq2, const unsigned short* __restrict__ Wk2,
    const unsigned short* __restrict__ Wv2,
    const float* __restrict__ bq, const float* __restrict__ bk,
    const float* __restrict__ bv,
    unsigned short* __restrict__ qo, unsigned short* __restrict__ ko,
    unsigned short* __restrict__ vo,
    int mode)
{
    // GEMM uses first 32768 B as 2 x (A 8KB + B 8KB) buffers.
    // Epilogue reuses all 36864 B as 4 x (64*72) transpose tiles.
    __shared__ __align__(16) short smem[4 * 64 * 72];

    const int tid = threadIdx.x, lane = tid & 63, wave = tid >> 6;
    const int wm = wave >> 1, wn = wave & 1;
    const int l15 = lane & 15, lq = lane >> 4;

    const int zz = blockIdx.x, tTile = blockIdx.y, oTile = blockIdx.z;
    int w, b;
    if (mode == 0)      { w = zz % 3;        b = zz / 3;  }
    else if (mode == 1) { w = 0;             b = zz;      }
    else                { w = 1 + (zz & 1);  b = zz >> 1; }
    const unsigned short* inT = (w == 0) ? xT : cT;
    const int oBase = oTile * 128, tBase = tTile * 128;

    const unsigned short* WA = (w == 0) ? Wq2 : (w == 1) ? Wk2 : Wv2;
    const float* bias        = (w == 0) ? bq  : (w == 1) ? bk  : bv;

    const int srow = lane >> 2;
    const int sch  = (lane ^ (lane >> 2) ^ (lane >> 4)) & 3;   // swizzled chunk
    const unsigned short* gA0 = WA + (size_t)(oBase + wave * 32 + srow) * CC + sch * 8;
    const unsigned short* gA1 = gA0 + (size_t)16 * CC;
    const unsigned short* gB0 = inT + ((size_t)b * TT + tBase + wave * 32 + srow) * CC + sch * 8;
    const unsigned short* gB1 = gB0 + (size_t)16 * CC;

    short* A0b = smem;            short* B0b = smem + 4096;
    short* A1b = smem + 8192;     short* B1b = smem + 12288;
    const int oA0 = (wave * 2 + 0) * 512;
    const int oA1 = (wave * 2 + 1) * 512;

    // un-swizzle offset for fragment reads (per-lane constant)
    const int csw = ((lq ^ (l15 & 3) ^ (l15 >> 2)) & 3) * 8;

    f32x4 acc[4][4];
    #pragma unroll
    for (int mt = 0; mt < 4; mt++)
        #pragma unroll
        for (int nt = 0; nt < 4; nt++) acc[mt][nt] = (f32x4){0.f, 0.f, 0.f, 0.f};

    auto stage = [&](int c0, short* dA, short* dB) {
        async16(gA0 + c0, dA + oA0);
        async16(gA1 + c0, dA + oA1);
        async16(gB0 + c0, dB + oA0);
        async16(gB1 + c0, dB + oA1);
    };
    auto compute = [&](const short* bA, const short* bB) {
        short8 af[4], bf[4];
        #pragma unroll
        for (int mt = 0; mt < 4; mt++)
            af[mt] = *(const short8*)(bA + (wm * 64 + mt * 16 + l15) * 32 + csw);
        #pragma unroll
        for (int nt = 0; nt < 4; nt++)
            bf[nt] = *(const short8*)(bB + (wn * 64 + nt * 16 + l15) * 32 + csw);
        #pragma unroll
        for (int mt = 0; mt < 4; mt++)
            #pragma unroll
            for (int nt = 0; nt < 4; nt++)
                acc[mt][nt] = mfma16(af[mt], bf[nt], acc[mt][nt]);
    };

    stage(0, A0b, B0b);                 // prologue: tile 0 -> buf0

    #pragma unroll 1
    for (int tt = 0; tt < 16; tt++) {
        const int c = tt * 64;
        // even step: compute buf0 (tile c), stage tile c+32 -> buf1
        asm volatile("s_waitcnt vmcnt(0)" ::: "memory");
        __builtin_amdgcn_s_barrier();
        __builtin_amdgcn_sched_barrier(0);
        stage(c + 32, A1b, B1b);        // c+32 <= 992 always valid
        compute(A0b, B0b);
        asm volatile("s_waitcnt lgkmcnt(0)" ::: "memory");

        // odd step: compute buf1 (tile c+32), stage tile c+64 -> buf0
        asm volatile("s_waitcnt vmcnt(0)" ::: "memory");
        __builtin_amdgcn_s_barrier();
        __builtin_amdgcn_sched_barrier(0);
        if (tt < 15) stage(c + 64, A0b, B0b);
        compute(A1b, B1b);
        asm volatile("s_waitcnt lgkmcnt(0)" ::: "memory");
    }
    __syncthreads();                    // all GEMM LDS reads retired everywhere

    // bias; fold QSCALE into q
    #pragma unroll
    for (int mt = 0; mt < 4; mt++)
        #pragma unroll
        for (int r = 0; r < 4; r++) {
            float bi = bias[oBase + wm * 64 + mt * 16 + lq * 4 + r];
            #pragma unroll
            for (int nt = 0; nt < 4; nt++) {
                acc[mt][nt][r] += bi;
                if (w == 0) acc[mt][nt][r] *= QSCALE;
            }
        }

    const int h = oTile * 2 + wm;
    short* sT = smem + wave * (64 * 72);

    if (w < 2) {
        // RoPE: d = lq*4+r; pair (d, d+16) = (mt=0, mt=1).
        #pragma unroll
        for (int r = 0; r < 4; r++) {
            float dr = (float)(lq * 4 + r);
            float theta = exp2f(dr * -0.8304820237f);
            float sa, ca, ss, cs;
            sincosf((float)(tBase + wn * 64 + l15) * theta, &sa, &ca);
            sincosf(16.0f * theta, &ss, &cs);
            #pragma unroll
            for (int nt = 0; nt < 4; nt++) {
                float x0 = acc[0][nt][r], x1 = acc[1][nt][r];
                acc[0][nt][r] = x0 * ca - x1 * sa;
                acc[1][nt][r] = x1 * ca + x0 * sa;
                float c2 = ca * cs - sa * ss;     // advance angle by 16*theta
                sa = sa * cs + ca * ss;
                ca = c2;
            }
        }
        #pragma unroll
        for (int nt = 0; nt < 4; nt++)
            #pragma unroll
            for (int mt = 0; mt < 4; mt++) {
                short4_ v4;
                #pragma unroll
                for (int r = 0; r < 4; r++) v4[r] = (short)f2bf(acc[mt][nt][r]);
                *(short4_*)(sT + (nt * 16 + l15) * 72 + mt * 16 + lq * 4) = v4;
            }
    } else {
        #pragma unroll
        for (int mt = 0; mt < 4; mt++)
            #pragma unroll
            for (int r = 0; r < 4; r++)
                #pragma unroll
                for (int nt = 0; nt < 4; nt++)
                    sT[(mt * 16 + lq * 4 + r) * 72 + nt * 16 + l15] =
                        (short)f2bf(acc[mt][nt][r]);
    }
    __asm__ volatile("s_waitcnt lgkmcnt(0)" ::: "memory");

    unsigned short* dstBase;
    if (w == 0)
        dstBase = qo + ((size_t)(b * HH + h) * TT + tBase + wn * 64 + lane) * DD;
    else if (w == 1)
        dstBase = ko + ((size_t)(b * HH + h) * TT + tBase + wn * 64 + lane) * DD;
    else
        dstBase = vo + ((size_t)(b * HH + h) * DD + lane) * TT + tBase + wn * 64;
    #pragma unroll
    for (int j = 0; j < 8; j++)
        *(short8*)(dstBase + j * 8) = *(short8*)(sT + lane * 72 + j * 8);
}

// ---------------------------------------------------------------------------
// O-proj GEMM, same 2-buffer single-barrier structure.
// Grid (b, tTile, oTile): id%8 = b%8 -> each XCD owns one batch; its att
// (2 MB) + Wo panels fit that XCD's L2.
// ---------------------------------------------------------------------------
__global__ __launch_bounds__(256) void oproj_gll_kernel(
    const unsigned short* __restrict__ att, const unsigned short* __restrict__ Wo2,
    const float* __restrict__ bo, float* __restrict__ out)
{
    __shared__ __align__(16) short smem[16384];   // 2 x (A 4096 + B 4096)

    const int tid = threadIdx.x, lane = tid & 63, wave = tid >> 6;
    const int wm = wave >> 1, wn = wave & 1;
    const int l15 = lane & 15, lq = lane >> 4;
    const int b = blockIdx.x, tTile = blockIdx.y, oTile = blockIdx.z;
    const int oBase = oTile * 128, tBase = tTile * 128;

    const int srow = lane >> 2;
    const int sch  = (lane ^ (lane >> 2) ^ (lane >> 4)) & 3;
    const unsigned short* gA0 = Wo2 + (size_t)(oBase + wave * 32 + srow) * CC + sch * 8;
    const unsigned short* gA1 = gA0 + (size_t)16 * CC;
    const unsigned short* attB = att + (size_t)b * HH * TT * DD;
    const int t0 = tBase + wave * 32 + srow;
    const int csch = sch * 8;

    short* A0b = smem;            short* B0b = smem + 4096;
    short* A1b = smem + 8192;     short* B1b = smem + 12288;
    const int oA0 = (wave * 2 + 0) * 512;
    const int oA1 = (wave * 2 + 1) * 512;

    const int csw = ((lq ^ (l15 & 3) ^ (l15 >> 2)) & 3) * 8;

    f32x4 acc[4][4];
    #pragma unroll
    for (int mt = 0; mt < 4; mt++)
        #pragma unroll
        for (int nt = 0; nt < 4; nt++) acc[mt][nt] = (f32x4){0.f, 0.f, 0.f, 0.f};

    auto stage = [&](int c0, short* dA, short* dB) {
        int c = c0 + csch;
        const unsigned short* g0 =
            attB + ((size_t)(c >> 6) * TT + t0) * DD + (c & 63);
        async16(gA0 + c0, dA + oA0);
        async16(gA1 + c0, dA + oA1);
        async16(g0, dB + oA0);
        async16(g0 + 16 * DD, dB + oA1);
    };
    auto compute = [&](const short* bA, const short* bB) {
        short8 af[4], bf[4];
        #pragma unroll
        for (int mt = 0; mt < 4; mt++)
            af[mt] = *(const short8*)(bA + (wm * 64 + mt * 16 + l15) * 32 + csw);
        #pragma unroll
        for (int nt = 0; nt < 4; nt++)
            bf[nt] = *(const short8*)(bB + (wn * 64 + nt * 16 + l15) * 32 + csw);
        #pragma unroll
        for (int mt = 0; mt < 4; mt++)
            #pragma unroll
            for (int nt = 0; nt < 4; nt++)
                acc[mt][nt] = mfma16(af[mt], bf[nt], acc[mt][nt]);
    };

    stage(0, A0b, B0b);

    #pragma unroll 1
    for (int tt = 0; tt < 16; tt++) {
        const int c = tt * 64;
        asm volatile("s_waitcnt vmcnt(0)" ::: "memory");
        __builtin_amdgcn_s_barrier();
        __builtin_amdgcn_sched_barrier(0);
        stage(c + 32, A1b, B1b);
        compute(A0b, B0b);
        asm volatile("s_waitcnt lgkmcnt(0)" ::: "memory");

        asm volatile("s_waitcnt vmcnt(0)" ::: "memory");
        __builtin_amdgcn_s_barrier();
        __builtin_amdgcn_sched_barrier(0);
        if (tt < 15) stage(c + 64, A0b, B0b);
        compute(A1b, B1b);
        asm volatile("s_waitcnt lgkmcnt(0)" ::: "memory");
    }

    #pragma unroll
    for (int mt = 0; mt < 4; mt++)
        #pragma unroll
        for (int r = 0; r < 4; r++) {
            int o = oBase + wm * 64 + mt * 16 + lq * 4 + r;
            float bi = bo[o];
            float* dst = out + ((size_t)b * CC + o) * TT + tBase + wn * 64;
            #pragma unroll
            for (int nt = 0; nt < 4; nt++)
                dst[nt * 16 + l15] = acc[mt][nt][r] + bi;
        }
}

// ---------------------------------------------------------------------------
// Flash attention v6 (grid re-ordered: bh fastest -> id%8 = bh%8, so each
// XCD streams its 16 bh's K/V once into L2; 16 qTiles of a bh hit L2):
//   - swapped QK^T (mfma(K,Q)): P lane-local along k, softmax in registers
//   - mask fast-path: block-uniform all-set check skips mask loads + cndmask
//   - denominator via ones-MFMA into accD
//   - V stored in LDS pre-permuted to the MFMA k-slot order
//   - exp2 via __builtin_amdgcn_exp2f
// ---------------------------------------------------------------------------
__global__ __launch_bounds__(256) void attn_mfma_kernel(
    const unsigned short* __restrict__ q, const unsigned short* __restrict__ k,
    const unsigned short* __restrict__ v, const int* __restrict__ mask,
    unsigned short* __restrict__ att)
{
    __shared__ __align__(16) short sQw[64 * 72];  // Q tile, then w-table (8 KB)
    __shared__ __align__(16) short sK[64 * 72];
    __shared__ __align__(16) short sV[64 * 72];   // V permuted: [d][x]
    __shared__ int sOK[4];

    const int tid = threadIdx.x, lane = tid & 63, wq = tid >> 6;
    const int l15 = lane & 15, lq = lane >> 4;
    const int bh = blockIdx.x, qTile = blockIdx.y, b = bh >> 4;

    const int sr = tid >> 2, sc = (tid & 3) * 16;
    const int* maskB = mask + b * TT;

    // block-uniform mask check: each thread covers 4 entries
    {
        i32x4 m4 = *(const i32x4*)(maskB + tid * 4);
        int ok = (m4[0] != 0) & (m4[1] != 0) & (m4[2] != 0) & (m4[3] != 0);
        unsigned long long bal = __ballot(ok);
        if (lane == 0) sOK[wq] = (bal == ~0ull);
    }

    {
        const unsigned short* gq = q + ((size_t)bh * TT + qTile * 64 + sr) * DD + sc;
        *(short8*)(sQw + sr * 72 + sc)     = *(const short8*)gq;
        *(short8*)(sQw + sr * 72 + sc + 8) = *(const short8*)(gq + 8);
    }
    __syncthreads();

    // Q fragments (B-operand of the swapped QK^T): lane holds Q[q=l15][d=lq*8..]
    const short8 bq0 = *(short8*)(sQw + (wq * 16 + l15) * 72 + lq * 8);
    const short8 bq1 = *(short8*)(sQw + (wq * 16 + l15) * 72 + 32 + lq * 8);
    const bool allOK = sOK[0] && sOK[1] && sOK[2] && sOK[3];
    __syncthreads();   // all waves done reading sQw before table overwrite

    float* wtab = (float*)sQw;
    #pragma unroll
    for (int j = 0; j < 8; j++) {
        int d = tid + 256 * j;                 // 0..2047
        int ad = d - 1023; ad = ad < 0 ? -ad : ad;
        wtab[d] = __builtin_amdgcn_rcpf(1.0f + (float)ad);
    }
    // visibility guaranteed by the first barrier inside the K-loop

    // all-ones bf16 B-fragment for the denominator MFMA
    short8 vones;
    #pragma unroll
    for (int e = 0; e < 8; e++) vones[e] = (short)0x3F80;

    f32x4 accO[4];
    #pragma unroll
    for (int nt = 0; nt < 4; nt++) accO[nt] = (f32x4){0.f, 0.f, 0.f, 0.f};
    f32x4 accD = (f32x4){0.f, 0.f, 0.f, 0.f};

    const int qpos = qTile * 64 + wq * 16 + l15;   // this lane's q
    const unsigned short* kB = k + (size_t)bh * TT * DD;
    const unsigned short* vB = v + (size_t)bh * DD * TT;

    // V staging: per-thread constant permuted offsets
    // thread covers k' = sc..sc+15 at row d=sr; group j (4 k's) -> x = j*16+xo
    const int xo = ((tid & 3) >> 1) * 8 + (tid & 1) * 4;
    short* vwp = sV + sr * 72 + xo;

    // software-pipelined K/V loads (tile kt staged while computing kt-1)
    const unsigned short* gk = kB + (size_t)sr * DD + sc;
    const unsigned short* gv = vB + (size_t)sr * TT + sc;
    short8 kr0 = *(const short8*)gk;
    short8 kr1 = *(const short8*)(gk + 8);
    short8 vr0 = *(const short8*)gv;
    short8 vr1 = *(const short8*)(gv + 8);

    for (int kt = 0; kt < 16; kt++) {
        __syncthreads();                       // prev tile fully consumed
        *(short8*)(sK + sr * 72 + sc)     = kr0;
        *(short8*)(sK + sr * 72 + sc + 8) = kr1;
        {
            u64x2 vv0 = __builtin_bit_cast(u64x2, vr0);
            u64x2 vv1 = __builtin_bit_cast(u64x2, vr1);
            *(unsigned long long*)(vwp)      = vv0[0];
            *(unsigned long long*)(vwp + 16) = vv0[1];
            *(unsigned long long*)(vwp + 32) = vv1[0];
            *(unsigned long long*)(vwp + 48) = vv1[1];
        }
        __syncthreads();

        if (kt < 15) {                         // prefetch next tile
            gk += 64 * DD;
            gv += 64;
            kr0 = *(const short8*)gk;
            kr1 = *(const short8*)(gk + 8);
            vr0 = *(const short8*)gv;
            vr1 = *(const short8*)(gv + 8);
        }

        // S^T = K·Q^T : lane holds S[k = kt*64 + nt*16 + lq*4 + r][q = qpos]
        f32x4 s4[4];
        #pragma unroll
        for (int nt = 0; nt < 4; nt++) {
            short8 ka0 = *(short8*)(sK + (nt * 16 + l15) * 72 + lq * 8);
            short8 ka1 = *(short8*)(sK + (nt * 16 + l15) * 72 + 32 + lq * 8);
            f32x4 z = (f32x4){0.f, 0.f, 0.f, 0.f};
            z = mfma16(ka0, bq0, z);
            z = mfma16(ka1, bq1, z);
            s4[nt] = z;
        }

        // p = exp2(s) * w[Dt+1023]; fast path skips masking entirely
        const float* wrow = wtab + (kt * 64 + lq * 4 + 1023 - qpos);
        unsigned pk8[4][2];
        if (allOK) {
            #pragma unroll
            for (int nt = 0; nt < 4; nt++) {
                #pragma unroll
                for (int h2 = 0; h2 < 2; h2++) {
                    float p0 = __builtin_amdgcn_exp2f(s4[nt][2 * h2])
                               * wrow[nt * 16 + 2 * h2];
                    float p1 = __builtin_amdgcn_exp2f(s4[nt][2 * h2 + 1])
                               * wrow[nt * 16 + 2 * h2 + 1];
                    pk8[nt][h2] = cvtpk(p0, p1);
                }
            }
        } else {
            #pragma unroll
            for (int nt = 0; nt < 4; nt++) {
                i32x4 mk = *(const i32x4*)(maskB + kt * 64 + nt * 16 + lq * 4);
                #pragma unroll
                for (int h2 = 0; h2 < 2; h2++) {
                    float p0 = __builtin_amdgcn_exp2f(s4[nt][2 * h2])
                               * wrow[nt * 16 + 2 * h2];
                    float p1 = __builtin_amdgcn_exp2f(s4[nt][2 * h2 + 1])
                               * wrow[nt * 16 + 2 * h2 + 1];
                    p0 = mk[2 * h2]     ? p0 : 0.f;
                    p1 = mk[2 * h2 + 1] ? p1 : 0.f;
                    pk8[nt][h2] = cvtpk(p0, p1);
                }
            }
        }

        // A-fragments for PV directly from the lane's own k-slots:
        // slot (lq, e, frag) <-> k = frag*32 + (e>>2)*16 + lq*4 + (e&3)
        i32x4 c0 = {(int)pk8[0][0], (int)pk8[0][1], (int)pk8[1][0], (int)pk8[1][1]};
        i32x4 c1 = {(int)pk8[2][0], (int)pk8[2][1], (int)pk8[3][0], (int)pk8[3][1]};
        short8 ap0 = __builtin_bit_cast(short8, c0);
        short8 ap1 = __builtin_bit_cast(short8, c1);

        // denominator: P · ones (every output column = row-sum of P)
        accD = mfma16(ap0, vones, accD);
        accD = mfma16(ap1, vones, accD);

        // V fragments: permuted layout makes them two aligned b128 reads
        #pragma unroll
        for (int nt = 0; nt < 4; nt++) {
            const short* vrow = sV + (nt * 16 + l15) * 72 + lq * 16;
            short8 b0 = *(short8*)(vrow);      // frag 0: k in [0,32)
            short8 b1 = *(short8*)(vrow + 8);  // frag 1: k in [32,64)
            accO[nt] = mfma16(ap0, b0, accO[nt]);
            accO[nt] = mfma16(ap1, b1, accO[nt]);
        }
    }

    // accD[r] = denom(q = wq*16 + lq*4 + r), exactly this lane's output rows
    unsigned short* aB = att + ((size_t)bh * TT + qTile * 64 + wq * 16 + lq * 4) * DD;
    #pragma unroll
    for (int r = 0; r < 4; r++) {
        float inv = 1.0f / accD[r];
        #pragma unroll
        for (int nt = 0; nt < 4; nt++)
            aB[(size_t)r * DD + nt * 16 + l15] = f2bf(accO[nt][r] * inv);
    }
}

// ---------------------------------------------------------------------------
// Legacy fallback kernels (used only if ws < 72 MB). q pre-scaled.
// ---------------------------------------------------------------------------
__global__ __launch_bounds__(256) void qkv_mfma_kernel(
    const float* __restrict__ x, const float* __restrict__ ctx,
    const float* __restrict__ Wq, const float* __restrict__ bq,
    const float* __restrict__ Wk, const float* __restrict__ bk,
    const float* __restrict__ Wv, const float* __restrict__ bv,
    unsigned short* __restrict__ qo, unsigned short* __restrict__ ko,
    unsigned short* __restrict__ vo)
{
    __shared__ __align__(16) short smem[4 * 64 * 72];
    short* sA = smem;
    short* sB = smem + 128 * 40;

    const int tid  = threadIdx.x;
    const int lane = tid & 63;
    const int wave = tid >> 6;
    const int wm = wave >> 1, wn = wave & 1;
    const int l15 = lane & 15, lq = lane >> 4;

    const int tTile = blockIdx.x, oTile = blockIdx.y;
    const int b = blockIdx.z / 3, w = blockIdx.z % 3;
    const int oBase = oTile * 128, tBase = tTile * 128;

    const float* In   = (w == 0) ? x  : ctx;
    const float* W    = (w == 0) ? Wq : (w == 1) ? Wk : Wv;
    const float* bias = (w == 0) ? bq : (w == 1) ? bk : bv;
    const float* InB  = In + (size_t)b * CC * TT;

    const int ao = tid >> 1, ak = (tid & 1) * 16;
    const int bt = tid & 127, bk_ = (tid >> 7) * 16;
    const float* gA = W + (size_t)(oBase + ao) * CC + ak;
    const float* gB = InB + (size_t)bk_ * TT + tBase + bt;

    f32x4 acc[4][4];
    #pragma unroll
    for (int mt = 0; mt < 4; mt++)
        #pragma unroll
        for (int nt = 0; nt < 4; nt++) acc[mt][nt] = (f32x4){0.f, 0.f, 0.f, 0.f};

    for (int c0 = 0; c0 < CC; c0 += 32) {
        float fa[16], fb[16];
        #pragma unroll
        for (int i = 0; i < 4; i++) {
            float4 t4 = *(const float4*)(gA + c0 + 4 * i);
            fa[4*i+0] = t4.x; fa[4*i+1] = t4.y; fa[4*i+2] = t4.z; fa[4*i+3] = t4.w;
        }
        #pragma unroll
        for (int j = 0; j < 16; j++)
            fb[j] = gB[(size_t)(c0 + j) * TT];

        __syncthreads();
        short8 pa0, pa1, pb0, pb1;
        #pragma unroll
        for (int e = 0; e < 8; e++) {
            pa0[e] = (short)f2bf(fa[e]);   pa1[e] = (short)f2bf(fa[8 + e]);
            pb0[e] = (short)f2bf(fb[e]);   pb1[e] = (short)f2bf(fb[8 + e]);
        }
        *(short8*)(sA + ao * 40 + ak)     = pa0;
        *(short8*)(sA + ao * 40 + ak + 8) = pa1;
        *(short8*)(sB + bt * 40 + bk_)     = pb0;
        *(short8*)(sB + bt * 40 + bk_ + 8) = pb1;
        __syncthreads();

        short8 af[4], bf[4];
        #pragma unroll
        for (int mt = 0; mt < 4; mt++)
            af[mt] = *(short8*)(sA + (wm * 64 + mt * 16 + l15) * 40 + lq * 8);
        #pragma unroll
        for (int nt = 0; nt < 4; nt++)
            bf[nt] = *(short8*)(sB + (wn * 64 + nt * 16 + l15) * 40 + lq * 8);
        #pragma unroll
        for (int mt = 0; mt < 4; mt++)
            #pragma unroll
            for (int nt = 0; nt < 4; nt++)
                acc[mt][nt] = mfma16(af[mt], bf[nt], acc[mt][nt]);
    }

    #pragma unroll
    for (int mt = 0; mt < 4; mt++)
        #pragma unroll
        for (int r = 0; r < 4; r++) {
            float bi = bias[oBase + wm * 64 + mt * 16 + lq * 4 + r];
            #pragma unroll
            for (int nt = 0; nt < 4; nt++) {
                acc[mt][nt][r] += bi;
                if (w == 0) acc[mt][nt][r] *= QSCALE;
            }
        }

    const int h = oTile * 2 + wm;
    __syncthreads();
    short* sT = smem + wave * (64 * 72);

    if (w < 2) {
        #pragma unroll
        for (int r = 0; r < 4; r++) {
            float theta = powf(10000.0f, -(float)(lq * 4 + r) * (1.0f / 16.0f));
            #pragma unroll
            for (int nt = 0; nt < 4; nt++) {
                float tpos = (float)(tBase + wn * 64 + nt * 16 + l15);
                float sa, ca;
                sincosf(tpos * theta, &sa, &ca);
                float x0 = acc[0][nt][r], x1 = acc[1][nt][r];
                acc[0][nt][r] = x0 * ca - x1 * sa;
                acc[1][nt][r] = x1 * ca + x0 * sa;
            }
        }
        #pragma unroll
        for (int nt = 0; nt < 4; nt++)
            #pragma unroll
            for (int mt = 0; mt < 4; mt++) {
                short4_ v4;
                #pragma unroll
                for (int r = 0; r < 4; r++) v4[r] = (short)f2bf(acc[mt][nt][r]);
                *(short4_*)(sT + (nt * 16 + l15) * 72 + mt * 16 + lq * 4) = v4;
            }
    } else {
        #pragma unroll
        for (int mt = 0; mt < 4; mt++)
            #pragma unroll
            for (int r = 0; r < 4; r++)
                #pragma unroll
                for (int nt = 0; nt < 4; nt++)
                    sT[(mt * 16 + lq * 4 + r) * 72 + nt * 16 + l15] =
                        (short)f2bf(acc[mt][nt][r]);
    }
    __asm__ volatile("s_waitcnt lgkmcnt(0)" ::: "memory");

    unsigned short* dstBase;
    if (w == 0)
        dstBase = qo + ((size_t)(b * HH + h) * TT + tBase + wn * 64 + lane) * DD;
    else if (w == 1)
        dstBase = ko + ((size_t)(b * HH + h) * TT + tBase + wn * 64 + lane) * DD;
    else
        dstBase = vo + ((size_t)(b * HH + h) * DD + lane) * TT + tBase + wn * 64;
    #pragma unroll
    for (int j = 0; j < 8; j++)
        *(short8*)(dstBase + j * 8) = *(short8*)(sT + lane * 72 + j * 8);
}

__global__ __launch_bounds__(256) void oproj_mfma_kernel(
    const unsigned short* __restrict__ att, const float* __restrict__ Wo,
    const float* __restrict__ bo, float* __restrict__ out)
{
    __shared__ __align__(16) short smem[2 * 128 * 40];
    short* sA = smem;
    short* sB = smem + 128 * 40;

    const int tid = threadIdx.x, lane = tid & 63, wave = tid >> 6;
    const int wm = wave >> 1, wn = wave & 1;
    const int l15 = lane & 15, lq = lane >> 4;
    const int tTile = blockIdx.x, oTile = blockIdx.y, b = blockIdx.z;
    const int oBase = oTile * 128, tBase = tTile * 128;

    const int ao = tid >> 1, ak = (tid & 1) * 16;
    const int bt = tid & 127, bk_ = (tid >> 7) * 16;
    const float* gA = Wo + (size_t)(oBase + ao) * CC + ak;

    f32x4 acc[4][4];
    #pragma unroll
    for (int mt = 0; mt < 4; mt++)
        #pragma unroll
        for (int nt = 0; nt < 4; nt++) acc[mt][nt] = (f32x4){0.f, 0.f, 0.f, 0.f};

    for (int c0 = 0; c0 < CC; c0 += 32) {
        float fa[16];
        #pragma unroll
        for (int i = 0; i < 4; i++) {
            float4 t4 = *(const float4*)(gA + c0 + 4 * i);
            fa[4*i+0] = t4.x; fa[4*i+1] = t4.y; fa[4*i+2] = t4.z; fa[4*i+3] = t4.w;
        }
        int c = c0 + bk_;
        const unsigned short* gB =
            att + (((size_t)b * HH + (c >> 6)) * TT + tBase + bt) * DD + (c & 63);
        short8 pb0 = *(const short8*)gB;
        short8 pb1 = *(const short8*)(gB + 8);

        __syncthreads();
        short8 pa0, pa1;
        #pragma unroll
        for (int e = 0; e < 8; e++) {
            pa0[e] = (short)f2bf(fa[e]); pa1[e] = (short)f2bf(fa[8 + e]);
        }
        *(short8*)(sA + ao * 40 + ak)      = pa0;
        *(short8*)(sA + ao * 40 + ak + 8)  = pa1;
        *(short8*)(sB + bt * 40 + bk_)     = pb0;
        *(short8*)(sB + bt * 40 + bk_ + 8) = pb1;
        __syncthreads();

        short8 af[4], bf[4];
        #pragma unroll
        for (int mt = 0; mt < 4; mt++)
            af[mt] = *(short8*)(sA + (wm * 64 + mt * 16 + l15) * 40 + lq * 8);
        #pragma unroll
        for (int nt = 0; nt < 4; nt++)
            bf[nt] = *(short8*)(sB + (wn * 64 + nt * 16 + l15) * 40 + lq * 8);
        #pragma unroll
        for (int mt = 0; mt < 4; mt++)
            #pragma unroll
            for (int nt = 0; nt < 4; nt++)
                acc[mt][nt] = mfma16(af[mt], bf[nt], acc[mt][nt]);
    }

    #pragma unroll
    for (int mt = 0; mt < 4; mt++)
        #pragma unroll
        for (int r = 0; r < 4; r++) {
            int o = oBase + wm * 64 + mt * 16 + lq * 4 + r;
            float bi = bo[o];
            float* dst = out + ((size_t)b * CC + o) * TT + tBase + wn * 64;
            #pragma unroll
            for (int nt = 0; nt < 4; nt++)
                dst[nt * 16 + l15] = acc[mt][nt][r] + bi;
        }
}

// ---------------------------------------------------------------------------
extern "C" void kernel_launch(void* const* d_in, const int* in_sizes, int n_in,
                              void* d_out, int out_size, void* d_ws, size_t ws_size,
                              hipStream_t stream)
{
    const float* x   = (const float*)d_in[0];
    const float* ctx = (const float*)d_in[1];
    const int* mask  = (const int*)d_in[2];
    const float* Wq  = (const float*)d_in[3];
    const float* bq  = (const float*)d_in[4];
    const float* Wk  = (const float*)d_in[5];
    const float* bk  = (const float*)d_in[6];
    const float* Wv  = (const float*)d_in[7];
    const float* bv  = (const float*)d_in[8];
    const float* Wo  = (const float*)d_in[9];
    const float* bo  = (const float*)d_in[10];
    float* out = (float*)d_out;

    const size_t nq = (size_t)BB * HH * TT * DD;        // 8M elems (16 MB bf16)
    const size_t nw = (size_t)CC * CC;                  // 1M elems

    if (ws_size >= (5 * nq + 4 * nw) * sizeof(unsigned short)) {
        // 88 MB: merged-qkv path (xT and ctxT both resident)
        unsigned short* q   = (unsigned short*)d_ws;    // [b,h,t,d] (pre-scaled)
        unsigned short* k   = q + nq;                   // [b,h,t,d]
        unsigned short* v   = k + nq;                   // [b,h,d,t]
        unsigned short* xT  = v + nq;                   // later reused as att
        unsigned short* cT  = xT + nq;
        unsigned short* Wb  = cT + nq;
        unsigned short* Wqb = Wb;
        unsigned short* Wkb = Wb + nw;
        unsigned short* Wvb = Wb + 2 * nw;
        unsigned short* Wob = Wb + 3 * nw;

        cast_w_kernel<<<dim3(1024, 4), 256, 0, stream>>>(Wq, Wk, Wv, Wo, Wb);
        tcast2_kernel<<<dim3(16, 16, BB * 2), 256, 0, stream>>>(x, ctx, xT, cT);
        qkv_gll_kernel<<<dim3(BB * 3, 8, 8), 256, 0, stream>>>(
            xT, cT, Wqb, Wkb, Wvb, bq, bk, bv, q, k, v, 0);
        attn_mfma_kernel<<<dim3(BB * HH, TT / 64), 256, 0, stream>>>(
            q, k, v, mask, xT);
        oproj_gll_kernel<<<dim3(BB, 8, 8), 256, 0, stream>>>(xT, Wob, bo, out);
    } else if (ws_size >= (4 * nq + 4 * nw) * sizeof(unsigned short)) {
        // 72 MB: sequential-qkv path (buf reused xT -> ctxT -> att)
        unsigned short* q   = (unsigned short*)d_ws;
        unsigned short* k   = q + nq;
        unsigned short* v   = k + nq;
        unsigned short* buf = v + nq;
        unsigned short* Wb  = buf + nq;
        unsigned short* Wqb = Wb;
        unsigned short* Wkb = Wb + nw;
        unsigned short* Wvb = Wb + 2 * nw;
        unsigned short* Wob = Wb + 3 * nw;

        cast_w_kernel<<<dim3(1024, 4), 256, 0, stream>>>(Wq, Wk, Wv, Wo, Wb);
        tcast_kernel<<<dim3(16, 16, BB), 256, 0, stream>>>(x, buf);
        qkv_gll_kernel<<<dim3(BB, 8, 8), 256, 0, stream>>>(
            buf, buf, Wqb, Wkb, Wvb, bq, bk, bv, q, k, v, 1);
        tcast_kernel<<<dim3(16, 16, BB), 256, 0, stream>>>(ctx, buf);
        qkv_gll_kernel<<<dim3(BB * 2, 8, 8), 256, 0, stream>>>(
            buf, buf, Wqb, Wkb, Wvb, bq, bk, bv, q, k, v, 2);
        attn_mfma_kernel<<<dim3(BB * HH, TT / 64), 256, 0, stream>>>(
            q, k, v, mask, buf);
        oproj_gll_kernel<<<dim3(BB, 8, 8), 256, 0, stream>>>(buf, Wob, bo, out);
    } else {
        // 64 MB legacy fallback
        unsigned short* q   = (unsigned short*)d_ws;
        unsigned short* k   = q + nq;
        unsigned short* v   = k + nq;
        unsigned short* att = v + nq;
        qkv_mfma_kernel<<<dim3(8, 8, BB * 3), 256, 0, stream>>>(
            x, ctx, Wq, bq, Wk, bk, Wv, bv, q, k, v);
        attn_mfma_kernel<<<dim3(BB * HH, TT / 64), 256, 0, stream>>>(
            q, k, v, mask, att);
        oproj_mfma_kernel<<<dim3(8, 8, BB), 256, 0, stream>>>(att, Wo, bo, out);
    }
}

// Round 6
// 295.198 us; speedup vs baseline: 1.0273x; 1.0273x over previous
//
#include <hip/hip_runtime.h>
#include <hip/hip_bf16.h>
#include <math.h>

#define BB 8
#define CC 1024
#define TT 1024
#define HH 16
#define DD 64

typedef __attribute__((ext_vector_type(8))) short short8;
typedef __attribute__((ext_vector_type(4))) short short4_;
typedef __attribute__((ext_vector_type(4))) float f32x4;
typedef __attribute__((ext_vector_type(4))) int   i32x4;
typedef __attribute__((ext_vector_type(2))) unsigned long long u64x2;

#define QSCALE 0.18033688f   /* 0.125 * log2(e) */

__device__ __forceinline__ unsigned short f2bf(float f) {
    unsigned u = __builtin_bit_cast(unsigned, f);
    u += 0x7fffu + ((u >> 16) & 1u);
    return (unsigned short)(u >> 16);
}

__device__ __forceinline__ f32x4 mfma16(short8 a, short8 b, f32x4 c) {
    return __builtin_amdgcn_mfma_f32_16x16x32_bf16(a, b, c, 0, 0, 0);
}

// async global->LDS, 16B per lane; LDS dest = base + lane*16 (wave-uniform base)
__device__ __forceinline__ void async16(const void* g, void* l) {
    __builtin_amdgcn_global_load_lds(
        (const __attribute__((address_space(1))) unsigned int*)g,
        (__attribute__((address_space(3))) unsigned int*)l, 16, 0, 0);
}

// pack two f32 -> one dword of two bf16 (low = lo, high = hi)
__device__ __forceinline__ unsigned cvtpk(float lo, float hi) {
    unsigned r;
    asm("v_cvt_pk_bf16_f32 %0, %1, %2" : "=v"(r) : "v"(lo), "v"(hi));
    return r;
}

// ---------------------------------------------------------------------------
// Pre-pass A: cast the four weight matrices fp32 -> bf16 (concat at dst)
// ---------------------------------------------------------------------------
__global__ __launch_bounds__(256) void cast_w_kernel(
    const float* __restrict__ Wq, const float* __restrict__ Wk,
    const float* __restrict__ Wv, const float* __restrict__ Wo,
    unsigned short* __restrict__ dst)
{
    const int z = blockIdx.y;
    const float* W = (z == 0) ? Wq : (z == 1) ? Wk : (z == 2) ? Wv : Wo;
    unsigned short* d = dst + (size_t)z * CC * CC;
    int idx = blockIdx.x * 256 + threadIdx.x;
    float4 f = ((const float4*)W)[idx];
    short4_ s;
    s[0] = (short)f2bf(f.x); s[1] = (short)f2bf(f.y);
    s[2] = (short)f2bf(f.z); s[3] = (short)f2bf(f.w);
    ((short4_*)d)[idx] = s;
}

// ---------------------------------------------------------------------------
// Pre-pass B: transpose+cast both inputs  [b][c][t] fp32 -> [b][t][c] bf16
// grid (T/64, C/64, 2*B): z<B -> x, else ctx.
// ---------------------------------------------------------------------------
__global__ __launch_bounds__(256) void tcast2_kernel(
    const float* __restrict__ x, const float* __restrict__ ctx,
    unsigned short* __restrict__ xT, unsigned short* __restrict__ cTo)
{
    __shared__ float sT[64][65];
    const int tid = threadIdx.x;
    const int z = blockIdx.z;
    const float* in = (z < BB) ? x : ctx;
    unsigned short* out = (z < BB) ? xT : cTo;
    const int b = (z < BB) ? z : z - BB;
    const int tB = blockIdx.x * 64, cT = blockIdx.y * 64;

    const float* ib = in + ((size_t)b * CC + cT) * TT + tB;
    const int r = tid >> 2;
    #pragma unroll
    for (int j = 0; j < 4; j++) {
        int t4 = (tid & 3) * 4 + j * 16;
        float4 f = *(const float4*)(ib + (size_t)r * TT + t4);
        sT[r][t4 + 0] = f.x; sT[r][t4 + 1] = f.y;
        sT[r][t4 + 2] = f.z; sT[r][t4 + 3] = f.w;
    }
    __syncthreads();
    const int t_l = tid >> 2, cch = (tid & 3) * 16;
    short8 o0, o1;
    #pragma unroll
    for (int i = 0; i < 8; i++) {
        o0[i] = (short)f2bf(sT[cch + i][t_l]);
        o1[i] = (short)f2bf(sT[cch + 8 + i][t_l]);
    }
    unsigned short* dp = out + ((size_t)b * TT + tB + t_l) * CC + cT + cch;
    *(short8*)dp = o0;
    *(short8*)(dp + 8) = o1;
}

// single-input variant for the 72 MB fallback path
__global__ __launch_bounds__(256) void tcast_kernel(
    const float* __restrict__ in, unsigned short* __restrict__ out)
{
    __shared__ float sT[64][65];
    const int tid = threadIdx.x;
    const int tB = blockIdx.x * 64, cT = blockIdx.y * 64, b = blockIdx.z;

    const float* ib = in + ((size_t)b * CC + cT) * TT + tB;
    const int r = tid >> 2;
    #pragma unroll
    for (int j = 0; j < 4; j++) {
        int t4 = (tid & 3) * 4 + j * 16;
        float4 f = *(const float4*)(ib + (size_t)r * TT + t4);
        sT[r][t4 + 0] = f.x; sT[r][t4 + 1] = f.y;
        sT[r][t4 + 2] = f.z; sT[r][t4 + 3] = f.w;
    }
    __syncthreads();
    const int t_l = tid >> 2, cch = (tid & 3) * 16;
    short8 o0, o1;
    #pragma unroll
    for (int i = 0; i < 8; i++) {
        o0[i] = (short)f2bf(sT[cch + i][t_l]);
        o1[i] = (short)f2bf(sT[cch + 8 + i][t_l]);
    }
    unsigned short* dp = out + ((size_t)b * TT + tB + t_l) * CC + cT + cch;
    *(short8*)dp = o0;
    *(short8*)(dp + 8) = o1;
}

// ---------------------------------------------------------------------------
// QKV GEMM: 3-deep pipelined staging with counted vmcnt (round-4 config,
// measured 84 us / FETCH 92 MB). Prologue stages tiles 0,1; iteration t
// issues tile t+2, waits vmcnt(8) (= tile t's 4 loads done, 8 in flight),
// raw s_barrier, compute, lgkmcnt(0) + s_barrier. Issue->wait slack is 2
// full iterations. Grid (tTile, oTile, zz) — round-4 ordering (the round-5
// zz-fastest regrouping put 12 MB working sets on 4 MB L2s and regressed).
// mode 0: z -> (b=z/3, w=z%3).  mode 1: w=0, b=z.  mode 2: w=1+(z&1).
// Epilogue: bias + (w==0: fold QSCALE) + RoPE (rotation recurrence) + split.
// ---------------------------------------------------------------------------
__global__ __launch_bounds__(256) void qkv_gll_kernel(
    const unsigned short* __restrict__ xT, const unsigned short* __restrict__ cT,
    const unsigned short* __restrict__ Wq2, const unsigned short* __restrict__ Wk2,
    const unsigned short* __restrict__ Wv2,
    const float* __restrict__ bq, const float* __restrict__ bk,
    const float* __restrict__ bv,
    unsigned short* __restrict__ qo, unsigned short* __restrict__ ko,
    unsigned short* __restrict__ vo,
    int mode)
{
    // GEMM: 3 buffers x (A 4096 + B 4096 shorts) = 49152 B (3 blocks/CU).
    // Epilogue reuses first 36864 B as 4 x (64*72) transpose tiles.
    __shared__ __align__(16) short smem[3 * 8192];

    const int tid = threadIdx.x, lane = tid & 63, wave = tid >> 6;
    const int wm = wave >> 1, wn = wave & 1;
    const int l15 = lane & 15, lq = lane >> 4;

    const int tTile = blockIdx.x, oTile = blockIdx.y;
    const int zz = blockIdx.z;
    int w, b;
    if (mode == 0)      { w = zz % 3;        b = zz / 3;  }
    else if (mode == 1) { w = 0;             b = zz;      }
    else                { w = 1 + (zz & 1);  b = zz >> 1; }
    const unsigned short* inT = (w == 0) ? xT : cT;
    const int oBase = oTile * 128, tBase = tTile * 128;

    const unsigned short* WA = (w == 0) ? Wq2 : (w == 1) ? Wk2 : Wv2;
    const float* bias        = (w == 0) ? bq  : (w == 1) ? bk  : bv;

    const int srow = lane >> 2;
    const int sch  = (lane ^ (lane >> 2) ^ (lane >> 4)) & 3;   // swizzled chunk
    const unsigned short* gA0 = WA + (size_t)(oBase + wave * 32 + srow) * CC + sch * 8;
    const unsigned short* gA1 = gA0 + (size_t)16 * CC;
    const unsigned short* gB0 = inT + ((size_t)b * TT + tBase + wave * 32 + srow) * CC + sch * 8;
    const unsigned short* gB1 = gB0 + (size_t)16 * CC;

    // 3 rotating buffers: cur (compute), nx1 (next), nx2 (staging target)
    short* cA = smem;             short* cB = smem + 4096;
    short* nA = smem + 8192;      short* nB = smem + 12288;
    short* pA = smem + 16384;     short* pB = smem + 20480;
    const int oA0 = (wave * 2 + 0) * 512;
    const int oA1 = (wave * 2 + 1) * 512;

    // un-swizzle offset for fragment reads (per-lane constant)
    const int csw = ((lq ^ (l15 & 3) ^ (l15 >> 2)) & 3) * 8;

    f32x4 acc[4][4];
    #pragma unroll
    for (int mt = 0; mt < 4; mt++)
        #pragma unroll
        for (int nt = 0; nt < 4; nt++) acc[mt][nt] = (f32x4){0.f, 0.f, 0.f, 0.f};

    // prologue: stage tiles 0 and 1 (8 loads in flight per wave)
    async16(gA0, cA + oA0);       async16(gA1, cA + oA1);
    async16(gB0, cB + oA0);       async16(gB1, cB + oA1);
    async16(gA0 + 32, nA + oA0);  async16(gA1 + 32, nA + oA1);
    async16(gB0 + 32, nB + oA0);  async16(gB1 + 32, nB + oA1);

    for (int t = 0; t < 32; t++) {
        if (t < 30) {                 // stage tile t+2 into the spare buffer
            int c2 = (t + 2) * 32;
            async16(gA0 + c2, pA + oA0);
            async16(gA1 + c2, pA + oA1);
            async16(gB0 + c2, pB + oA0);
            async16(gB1 + c2, pB + oA1);
        }
        __builtin_amdgcn_sched_barrier(0);
        if (t < 30)       asm volatile("s_waitcnt vmcnt(8)" ::: "memory");
        else if (t == 30) asm volatile("s_waitcnt vmcnt(4)" ::: "memory");
        else              asm volatile("s_waitcnt vmcnt(0)" ::: "memory");
        __builtin_amdgcn_s_barrier();      // all waves' tile-t data in LDS
        __builtin_amdgcn_sched_barrier(0);

        short8 af[4], bf[4];
        #pragma unroll
        for (int mt = 0; mt < 4; mt++)
            af[mt] = *(short8*)(cA + (wm * 64 + mt * 16 + l15) * 32 + csw);
        #pragma unroll
        for (int nt = 0; nt < 4; nt++)
            bf[nt] = *(short8*)(cB + (wn * 64 + nt * 16 + l15) * 32 + csw);
        #pragma unroll
        for (int mt = 0; mt < 4; mt++)
            #pragma unroll
            for (int nt = 0; nt < 4; nt++)
                acc[mt][nt] = mfma16(af[mt], bf[nt], acc[mt][nt]);

        __builtin_amdgcn_sched_barrier(0);
        asm volatile("s_waitcnt lgkmcnt(0)" ::: "memory");  // reads retired
        __builtin_amdgcn_s_barrier();      // safe to re-stage cur 2 iters later

        short* tA = cA; cA = nA; nA = pA; pA = tA;
        short* tB = cB; cB = nB; nB = pB; pB = tB;
    }

    // bias; fold QSCALE into q
    #pragma unroll
    for (int mt = 0; mt < 4; mt++)
        #pragma unroll
        for (int r = 0; r < 4; r++) {
            float bi = bias[oBase + wm * 64 + mt * 16 + lq * 4 + r];
            #pragma unroll
            for (int nt = 0; nt < 4; nt++) {
                acc[mt][nt][r] += bi;
                if (w == 0) acc[mt][nt][r] *= QSCALE;
            }
        }

    const int h = oTile * 2 + wm;
    short* sT = smem + wave * (64 * 72);

    if (w < 2) {
        // RoPE: d = lq*4+r; pair (d, d+16) = (mt=0, mt=1).
        #pragma unroll
        for (int r = 0; r < 4; r++) {
            float dr = (float)(lq * 4 + r);
            float theta = exp2f(dr * -0.8304820237f);
            float sa, ca, ss, cs;
            sincosf((float)(tBase + wn * 64 + l15) * theta, &sa, &ca);
            sincosf(16.0f * theta, &ss, &cs);
            #pragma unroll
            for (int nt = 0; nt < 4; nt++) {
                float x0 = acc[0][nt][r], x1 = acc[1][nt][r];
                acc[0][nt][r] = x0 * ca - x1 * sa;
                acc[1][nt][r] = x1 * ca + x0 * sa;
                float c2 = ca * cs - sa * ss;     // advance angle by 16*theta
                sa = sa * cs + ca * ss;
                ca = c2;
            }
        }
        #pragma unroll
        for (int nt = 0; nt < 4; nt++)
            #pragma unroll
            for (int mt = 0; mt < 4; mt++) {
                short4_ v4;
                #pragma unroll
                for (int r = 0; r < 4; r++) v4[r] = (short)f2bf(acc[mt][nt][r]);
                *(short4_*)(sT + (nt * 16 + l15) * 72 + mt * 16 + lq * 4) = v4;
            }
    } else {
        #pragma unroll
        for (int mt = 0; mt < 4; mt++)
            #pragma unroll
            for (int r = 0; r < 4; r++)
                #pragma unroll
                for (int nt = 0; nt < 4; nt++)
                    sT[(mt * 16 + lq * 4 + r) * 72 + nt * 16 + l15] =
                        (short)f2bf(acc[mt][nt][r]);
    }
    __asm__ volatile("s_waitcnt lgkmcnt(0)" ::: "memory");

    unsigned short* dstBase;
    if (w == 0)
        dstBase = qo + ((size_t)(b * HH + h) * TT + tBase + wn * 64 + lane) * DD;
    else if (w == 1)
        dstBase = ko + ((size_t)(b * HH + h) * TT + tBase + wn * 64 + lane) * DD;
    else
        dstBase = vo + ((size_t)(b * HH + h) * DD + lane) * TT + tBase + wn * 64;
    #pragma unroll
    for (int j = 0; j < 8; j++)
        *(short8*)(dstBase + j * 8) = *(short8*)(sT + lane * 72 + j * 8);
}

// ---------------------------------------------------------------------------
// O-proj GEMM, 2-buffer single-barrier structure, b-fastest grid (round 5:
// id%8 = b%8 -> each XCD owns one batch; att[b] 2 MB + Wo panels ~ L2).
// ---------------------------------------------------------------------------
__global__ __launch_bounds__(256) void oproj_gll_kernel(
    const unsigned short* __restrict__ att, const unsigned short* __restrict__ Wo2,
    const float* __restrict__ bo, float* __restrict__ out)
{
    __shared__ __align__(16) short smem[16384];   // 2 x (A 4096 + B 4096)

    const int tid = threadIdx.x, lane = tid & 63, wave = tid >> 6;
    const int wm = wave >> 1, wn = wave & 1;
    const int l15 = lane & 15, lq = lane >> 4;
    const int b = blockIdx.x, tTile = blockIdx.y, oTile = blockIdx.z;
    const int oBase = oTile * 128, tBase = tTile * 128;

    const int srow = lane >> 2;
    const int sch  = (lane ^ (lane >> 2) ^ (lane >> 4)) & 3;
    const unsigned short* gA0 = Wo2 + (size_t)(oBase + wave * 32 + srow) * CC + sch * 8;
    const unsigned short* gA1 = gA0 + (size_t)16 * CC;
    const unsigned short* attB = att + (size_t)b * HH * TT * DD;
    const int t0 = tBase + wave * 32 + srow;
    const int csch = sch * 8;

    short* A0b = smem;            short* B0b = smem + 4096;
    short* A1b = smem + 8192;     short* B1b = smem + 12288;
    const int oA0 = (wave * 2 + 0) * 512;
    const int oA1 = (wave * 2 + 1) * 512;

    const int csw = ((lq ^ (l15 & 3) ^ (l15 >> 2)) & 3) * 8;

    f32x4 acc[4][4];
    #pragma unroll
    for (int mt = 0; mt < 4; mt++)
        #pragma unroll
        for (int nt = 0; nt < 4; nt++) acc[mt][nt] = (f32x4){0.f, 0.f, 0.f, 0.f};

    auto stage = [&](int c0, short* dA, short* dB) {
        int c = c0 + csch;
        const unsigned short* g0 =
            attB + ((size_t)(c >> 6) * TT + t0) * DD + (c & 63);
        async16(gA0 + c0, dA + oA0);
        async16(gA1 + c0, dA + oA1);
        async16(g0, dB + oA0);
        async16(g0 + 16 * DD, dB + oA1);
    };
    auto compute = [&](const short* bA, const short* bB) {
        short8 af[4], bf[4];
        #pragma unroll
        for (int mt = 0; mt < 4; mt++)
            af[mt] = *(const short8*)(bA + (wm * 64 + mt * 16 + l15) * 32 + csw);
        #pragma unroll
        for (int nt = 0; nt < 4; nt++)
            bf[nt] = *(const short8*)(bB + (wn * 64 + nt * 16 + l15) * 32 + csw);
        #pragma unroll
        for (int mt = 0; mt < 4; mt++)
            #pragma unroll
            for (int nt = 0; nt < 4; nt++)
                acc[mt][nt] = mfma16(af[mt], bf[nt], acc[mt][nt]);
    };

    stage(0, A0b, B0b);

    #pragma unroll 1
    for (int tt = 0; tt < 16; tt++) {
        const int c = tt * 64;
        asm volatile("s_waitcnt vmcnt(0)" ::: "memory");
        __builtin_amdgcn_s_barrier();
        __builtin_amdgcn_sched_barrier(0);
        stage(c + 32, A1b, B1b);
        compute(A0b, B0b);
        asm volatile("s_waitcnt lgkmcnt(0)" ::: "memory");

        asm volatile("s_waitcnt vmcnt(0)" ::: "memory");
        __builtin_amdgcn_s_barrier();
        __builtin_amdgcn_sched_barrier(0);
        if (tt < 15) stage(c + 64, A0b, B0b);
        compute(A1b, B1b);
        asm volatile("s_waitcnt lgkmcnt(0)" ::: "memory");
    }

    #pragma unroll
    for (int mt = 0; mt < 4; mt++)
        #pragma unroll
        for (int r = 0; r < 4; r++) {
            int o = oBase + wm * 64 + mt * 16 + lq * 4 + r;
            float bi = bo[o];
            float* dst = out + ((size_t)b * CC + o) * TT + tBase + wn * 64;
            #pragma unroll
            for (int nt = 0; nt < 4; nt++)
                dst[nt * 16 + l15] = acc[mt][nt][r] + bi;
        }
}

// ---------------------------------------------------------------------------
// Flash attention v6 (bh-fastest grid, round 5: id%8 = bh%8 -> each XCD
// streams its 16 bh's K/V once into L2; 16 qTiles of a bh hit L2):
//   - swapped QK^T (mfma(K,Q)): P lane-local along k, softmax in registers
//   - mask fast-path: block-uniform all-set check skips mask loads + cndmask
//   - denominator via ones-MFMA into accD
//   - V stored in LDS pre-permuted to the MFMA k-slot order
//   - exp2 via __builtin_amdgcn_exp2f
// ---------------------------------------------------------------------------
__global__ __launch_bounds__(256) void attn_mfma_kernel(
    const unsigned short* __restrict__ q, const unsigned short* __restrict__ k,
    const unsigned short* __restrict__ v, const int* __restrict__ mask,
    unsigned short* __restrict__ att)
{
    __shared__ __align__(16) short sQw[64 * 72];  // Q tile, then w-table (8 KB)
    __shared__ __align__(16) short sK[64 * 72];
    __shared__ __align__(16) short sV[64 * 72];   // V permuted: [d][x]
    __shared__ int sOK[4];

    const int tid = threadIdx.x, lane = tid & 63, wq = tid >> 6;
    const int l15 = lane & 15, lq = lane >> 4;
    const int bh = blockIdx.x, qTile = blockIdx.y, b = bh >> 4;

    const int sr = tid >> 2, sc = (tid & 3) * 16;
    const int* maskB = mask + b * TT;

    // block-uniform mask check: each thread covers 4 entries
    {
        i32x4 m4 = *(const i32x4*)(maskB + tid * 4);
        int ok = (m4[0] != 0) & (m4[1] != 0) & (m4[2] != 0) & (m4[3] != 0);
        unsigned long long bal = __ballot(ok);
        if (lane == 0) sOK[wq] = (bal == ~0ull);
    }

    {
        const unsigned short* gq = q + ((size_t)bh * TT + qTile * 64 + sr) * DD + sc;
        *(short8*)(sQw + sr * 72 + sc)     = *(const short8*)gq;
        *(short8*)(sQw + sr * 72 + sc + 8) = *(const short8*)(gq + 8);
    }
    __syncthreads();

    // Q fragments (B-operand of the swapped QK^T): lane holds Q[q=l15][d=lq*8..]
    const short8 bq0 = *(short8*)(sQw + (wq * 16 + l15) * 72 + lq * 8);
    const short8 bq1 = *(short8*)(sQw + (wq * 16 + l15) * 72 + 32 + lq * 8);
    const bool allOK = sOK[0] && sOK[1] && sOK[2] && sOK[3];
    __syncthreads();   // all waves done reading sQw before table overwrite

    float* wtab = (float*)sQw;
    #pragma unroll
    for (int j = 0; j < 8; j++) {
        int d = tid + 256 * j;                 // 0..2047
        int ad = d - 1023; ad = ad < 0 ? -ad : ad;
        wtab[d] = __builtin_amdgcn_rcpf(1.0f + (float)ad);
    }
    // visibility guaranteed by the first barrier inside the K-loop

    // all-ones bf16 B-fragment for the denominator MFMA
    short8 vones;
    #pragma unroll
    for (int e = 0; e < 8; e++) vones[e] = (short)0x3F80;

    f32x4 accO[4];
    #pragma unroll
    for (int nt = 0; nt < 4; nt++) accO[nt] = (f32x4){0.f, 0.f, 0.f, 0.f};
    f32x4 accD = (f32x4){0.f, 0.f, 0.f, 0.f};

    const int qpos = qTile * 64 + wq * 16 + l15;   // this lane's q
    const unsigned short* kB = k + (size_t)bh * TT * DD;
    const unsigned short* vB = v + (size_t)bh * DD * TT;

    // V staging: per-thread constant permuted offsets
    // thread covers k' = sc..sc+15 at row d=sr; group j (4 k's) -> x = j*16+xo
    const int xo = ((tid & 3) >> 1) * 8 + (tid & 1) * 4;
    short* vwp = sV + sr * 72 + xo;

    // software-pipelined K/V loads (tile kt staged while computing kt-1)
    const unsigned short* gk = kB + (size_t)sr * DD + sc;
    const unsigned short* gv = vB + (size_t)sr * TT + sc;
    short8 kr0 = *(const short8*)gk;
    short8 kr1 = *(const short8*)(gk + 8);
    short8 vr0 = *(const short8*)gv;
    short8 vr1 = *(const short8*)(gv + 8);

    for (int kt = 0; kt < 16; kt++) {
        __syncthreads();                       // prev tile fully consumed
        *(short8*)(sK + sr * 72 + sc)     = kr0;
        *(short8*)(sK + sr * 72 + sc + 8) = kr1;
        {
            u64x2 vv0 = __builtin_bit_cast(u64x2, vr0);
            u64x2 vv1 = __builtin_bit_cast(u64x2, vr1);
            *(unsigned long long*)(vwp)      = vv0[0];
            *(unsigned long long*)(vwp + 16) = vv0[1];
            *(unsigned long long*)(vwp + 32) = vv1[0];
            *(unsigned long long*)(vwp + 48) = vv1[1];
        }
        __syncthreads();

        if (kt < 15) {                         // prefetch next tile
            gk += 64 * DD;
            gv += 64;
            kr0 = *(const short8*)gk;
            kr1 = *(const short8*)(gk + 8);
            vr0 = *(const short8*)gv;
            vr1 = *(const short8*)(gv + 8);
        }

        // S^T = K·Q^T : lane holds S[k = kt*64 + nt*16 + lq*4 + r][q = qpos]
        f32x4 s4[4];
        #pragma unroll
        for (int nt = 0; nt < 4; nt++) {
            short8 ka0 = *(short8*)(sK + (nt * 16 + l15) * 72 + lq * 8);
            short8 ka1 = *(short8*)(sK + (nt * 16 + l15) * 72 + 32 + lq * 8);
            f32x4 z = (f32x4){0.f, 0.f, 0.f, 0.f};
            z = mfma16(ka0, bq0, z);
            z = mfma16(ka1, bq1, z);
            s4[nt] = z;
        }

        // p = exp2(s) * w[Dt+1023]; fast path skips masking entirely
        const float* wrow = wtab + (kt * 64 + lq * 4 + 1023 - qpos);
        unsigned pk8[4][2];
        if (allOK) {
            #pragma unroll
            for (int nt = 0; nt < 4; nt++) {
                #pragma unroll
                for (int h2 = 0; h2 < 2; h2++) {
                    float p0 = __builtin_amdgcn_exp2f(s4[nt][2 * h2])
                               * wrow[nt * 16 + 2 * h2];
                    float p1 = __builtin_amdgcn_exp2f(s4[nt][2 * h2 + 1])
                               * wrow[nt * 16 + 2 * h2 + 1];
                    pk8[nt][h2] = cvtpk(p0, p1);
                }
            }
        } else {
            #pragma unroll
            for (int nt = 0; nt < 4; nt++) {
                i32x4 mk = *(const i32x4*)(maskB + kt * 64 + nt * 16 + lq * 4);
                #pragma unroll
                for (int h2 = 0; h2 < 2; h2++) {
                    float p0 = __builtin_amdgcn_exp2f(s4[nt][2 * h2])
                               * wrow[nt * 16 + 2 * h2];
                    float p1 = __builtin_amdgcn_exp2f(s4[nt][2 * h2 + 1])
                               * wrow[nt * 16 + 2 * h2 + 1];
                    p0 = mk[2 * h2]     ? p0 : 0.f;
                    p1 = mk[2 * h2 + 1] ? p1 : 0.f;
                    pk8[nt][h2] = cvtpk(p0, p1);
                }
            }
        }

        // A-fragments for PV directly from the lane's own k-slots:
        // slot (lq, e, frag) <-> k = frag*32 + (e>>2)*16 + lq*4 + (e&3)
        i32x4 c0 = {(int)pk8[0][0], (int)pk8[0][1], (int)pk8[1][0], (int)pk8[1][1]};
        i32x4 c1 = {(int)pk8[2][0], (int)pk8[2][1], (int)pk8[3][0], (int)pk8[3][1]};
        short8 ap0 = __builtin_bit_cast(short8, c0);
        short8 ap1 = __builtin_bit_cast(short8, c1);

        // denominator: P · ones (every output column = row-sum of P)
        accD = mfma16(ap0, vones, accD);
        accD = mfma16(ap1, vones, accD);

        // V fragments: permuted layout makes them two aligned b128 reads
        #pragma unroll
        for (int nt = 0; nt < 4; nt++) {
            const short* vrow = sV + (nt * 16 + l15) * 72 + lq * 16;
            short8 b0 = *(short8*)(vrow);      // frag 0: k in [0,32)
            short8 b1 = *(short8*)(vrow + 8);  // frag 1: k in [32,64)
            accO[nt] = mfma16(ap0, b0, accO[nt]);
            accO[nt] = mfma16(ap1, b1, accO[nt]);
        }
    }

    // accD[r] = denom(q = wq*16 + lq*4 + r), exactly this lane's output rows
    unsigned short* aB = att + ((size_t)bh * TT + qTile * 64 + wq * 16 + lq * 4) * DD;
    #pragma unroll
    for (int r = 0; r < 4; r++) {
        float inv = 1.0f / accD[r];
        #pragma unroll
        for (int nt = 0; nt < 4; nt++)
            aB[(size_t)r * DD + nt * 16 + l15] = f2bf(accO[nt][r] * inv);
    }
}

// ---------------------------------------------------------------------------
// Legacy fallback kernels (used only if ws < 72 MB). q pre-scaled.
// ---------------------------------------------------------------------------
__global__ __launch_bounds__(256) void qkv_mfma_kernel(
    const float* __restrict__ x, const float* __restrict__ ctx,
    const float* __restrict__ Wq, const float* __restrict__ bq,
    const float* __restrict__ Wk, const float* __restrict__ bk,
    const float* __restrict__ Wv, const float* __restrict__ bv,
    unsigned short* __restrict__ qo, unsigned short* __restrict__ ko,
    unsigned short* __restrict__ vo)
{
    __shared__ __align__(16) short smem[4 * 64 * 72];
    short* sA = smem;
    short* sB = smem + 128 * 40;

    const int tid  = threadIdx.x;
    const int lane = tid & 63;
    const int wave = tid >> 6;
    const int wm = wave >> 1, wn = wave & 1;
    const int l15 = lane & 15, lq = lane >> 4;

    const int tTile = blockIdx.x, oTile = blockIdx.y;
    const int b = blockIdx.z / 3, w = blockIdx.z % 3;
    const int oBase = oTile * 128, tBase = tTile * 128;

    const float* In   = (w == 0) ? x  : ctx;
    const float* W    = (w == 0) ? Wq : (w == 1) ? Wk : Wv;
    const float* bias = (w == 0) ? bq : (w == 1) ? bk : bv;
    const float* InB  = In + (size_t)b * CC * TT;

    const int ao = tid >> 1, ak = (tid & 1) * 16;
    const int bt = tid & 127, bk_ = (tid >> 7) * 16;
    const float* gA = W + (size_t)(oBase + ao) * CC + ak;
    const float* gB = InB + (size_t)bk_ * TT + tBase + bt;

    f32x4 acc[4][4];
    #pragma unroll
    for (int mt = 0; mt < 4; mt++)
        #pragma unroll
        for (int nt = 0; nt < 4; nt++) acc[mt][nt] = (f32x4){0.f, 0.f, 0.f, 0.f};

    for (int c0 = 0; c0 < CC; c0 += 32) {
        float fa[16], fb[16];
        #pragma unroll
        for (int i = 0; i < 4; i++) {
            float4 t4 = *(const float4*)(gA + c0 + 4 * i);
            fa[4*i+0] = t4.x; fa[4*i+1] = t4.y; fa[4*i+2] = t4.z; fa[4*i+3] = t4.w;
        }
        #pragma unroll
        for (int j = 0; j < 16; j++)
            fb[j] = gB[(size_t)(c0 + j) * TT];

        __syncthreads();
        short8 pa0, pa1, pb0, pb1;
        #pragma unroll
        for (int e = 0; e < 8; e++) {
            pa0[e] = (short)f2bf(fa[e]);   pa1[e] = (short)f2bf(fa[8 + e]);
            pb0[e] = (short)f2bf(fb[e]);   pb1[e] = (short)f2bf(fb[8 + e]);
        }
        *(short8*)(sA + ao * 40 + ak)     = pa0;
        *(short8*)(sA + ao * 40 + ak + 8) = pa1;
        *(short8*)(sB + bt * 40 + bk_)     = pb0;
        *(short8*)(sB + bt * 40 + bk_ + 8) = pb1;
        __syncthreads();

        short8 af[4], bf[4];
        #pragma unroll
        for (int mt = 0; mt < 4; mt++)
            af[mt] = *(short8*)(sA + (wm * 64 + mt * 16 + l15) * 40 + lq * 8);
        #pragma unroll
        for (int nt = 0; nt < 4; nt++)
            bf[nt] = *(short8*)(sB + (wn * 64 + nt * 16 + l15) * 40 + lq * 8);
        #pragma unroll
        for (int mt = 0; mt < 4; mt++)
            #pragma unroll
            for (int nt = 0; nt < 4; nt++)
                acc[mt][nt] = mfma16(af[mt], bf[nt], acc[mt][nt]);
    }

    #pragma unroll
    for (int mt = 0; mt < 4; mt++)
        #pragma unroll
        for (int r = 0; r < 4; r++) {
            float bi = bias[oBase + wm * 64 + mt * 16 + lq * 4 + r];
            #pragma unroll
            for (int nt = 0; nt < 4; nt++) {
                acc[mt][nt][r] += bi;
                if (w == 0) acc[mt][nt][r] *= QSCALE;
            }
        }

    const int h = oTile * 2 + wm;
    __syncthreads();
    short* sT = smem + wave * (64 * 72);

    if (w < 2) {
        #pragma unroll
        for (int r = 0; r < 4; r++) {
            float theta = powf(10000.0f, -(float)(lq * 4 + r) * (1.0f / 16.0f));
            #pragma unroll
            for (int nt = 0; nt < 4; nt++) {
                float tpos = (float)(tBase + wn * 64 + nt * 16 + l15);
                float sa, ca;
                sincosf(tpos * theta, &sa, &ca);
                float x0 = acc[0][nt][r], x1 = acc[1][nt][r];
                acc[0][nt][r] = x0 * ca - x1 * sa;
                acc[1][nt][r] = x1 * ca + x0 * sa;
            }
        }
        #pragma unroll
        for (int nt = 0; nt < 4; nt++)
            #pragma unroll
            for (int mt = 0; mt < 4; mt++) {
                short4_ v4;
                #pragma unroll
                for (int r = 0; r < 4; r++) v4[r] = (short)f2bf(acc[mt][nt][r]);
                *(short4_*)(sT + (nt * 16 + l15) * 72 + mt * 16 + lq * 4) = v4;
            }
    } else {
        #pragma unroll
        for (int mt = 0; mt < 4; mt++)
            #pragma unroll
            for (int r = 0; r < 4; r++)
                #pragma unroll
                for (int nt = 0; nt < 4; nt++)
                    sT[(mt * 16 + lq * 4 + r) * 72 + nt * 16 + l15] =
                        (short)f2bf(acc[mt][nt][r]);
    }
    __asm__ volatile("s_waitcnt lgkmcnt(0)" ::: "memory");

    unsigned short* dstBase;
    if (w == 0)
        dstBase = qo + ((size_t)(b * HH + h) * TT + tBase + wn * 64 + lane) * DD;
    else if (w == 1)
        dstBase = ko + ((size_t)(b * HH + h) * TT + tBase + wn * 64 + lane) * DD;
    else
        dstBase = vo + ((size_t)(b * HH + h) * DD + lane) * TT + tBase + wn * 64;
    #pragma unroll
    for (int j = 0; j < 8; j++)
        *(short8*)(dstBase + j * 8) = *(short8*)(sT + lane * 72 + j * 8);
}

__global__ __launch_bounds__(256) void oproj_mfma_kernel(
    const unsigned short* __restrict__ att, const float* __restrict__ Wo,
    const float* __restrict__ bo, float* __restrict__ out)
{
    __shared__ __align__(16) short smem[2 * 128 * 40];
    short* sA = smem;
    short* sB = smem + 128 * 40;

    const int tid = threadIdx.x, lane = tid & 63, wave = tid >> 6;
    const int wm = wave >> 1, wn = wave & 1;
    const int l15 = lane & 15, lq = lane >> 4;
    const int tTile = blockIdx.x, oTile = blockIdx.y, b = blockIdx.z;
    const int oBase = oTile * 128, tBase = tTile * 128;

    const int ao = tid >> 1, ak = (tid & 1) * 16;
    const int bt = tid & 127, bk_ = (tid >> 7) * 16;
    const float* gA = Wo + (size_t)(oBase + ao) * CC + ak;

    f32x4 acc[4][4];
    #pragma unroll
    for (int mt = 0; mt < 4; mt++)
        #pragma unroll
        for (int nt = 0; nt < 4; nt++) acc[mt][nt] = (f32x4){0.f, 0.f, 0.f, 0.f};

    for (int c0 = 0; c0 < CC; c0 += 32) {
        float fa[16];
        #pragma unroll
        for (int i = 0; i < 4; i++) {
            float4 t4 = *(const float4*)(gA + c0 + 4 * i);
            fa[4*i+0] = t4.x; fa[4*i+1] = t4.y; fa[4*i+2] = t4.z; fa[4*i+3] = t4.w;
        }
        int c = c0 + bk_;
        const unsigned short* gB =
            att + (((size_t)b * HH + (c >> 6)) * TT + tBase + bt) * DD + (c & 63);
        short8 pb0 = *(const short8*)gB;
        short8 pb1 = *(const short8*)(gB + 8);

        __syncthreads();
        short8 pa0, pa1;
        #pragma unroll
        for (int e = 0; e < 8; e++) {
            pa0[e] = (short)f2bf(fa[e]); pa1[e] = (short)f2bf(fa[8 + e]);
        }
        *(short8*)(sA + ao * 40 + ak)      = pa0;
        *(short8*)(sA + ao * 40 + ak + 8)  = pa1;
        *(short8*)(sB + bt * 40 + bk_)     = pb0;
        *(short8*)(sB + bt * 40 + bk_ + 8) = pb1;
        __syncthreads();

        short8 af[4], bf[4];
        #pragma unroll
        for (int mt = 0; mt < 4; mt++)
            af[mt] = *(short8*)(sA + (wm * 64 + mt * 16 + l15) * 40 + lq * 8);
        #pragma unroll
        for (int nt = 0; nt < 4; nt++)
            bf[nt] = *(short8*)(sB + (wn * 64 + nt * 16 + l15) * 40 + lq * 8);
        #pragma unroll
        for (int mt = 0; mt < 4; mt++)
            #pragma unroll
            for (int nt = 0; nt < 4; nt++)
                acc[mt][nt] = mfma16(af[mt], bf[nt], acc[mt][nt]);
    }

    #pragma unroll
    for (int mt = 0; mt < 4; mt++)
        #pragma unroll
        for (int r = 0; r < 4; r++) {
            int o = oBase + wm * 64 + mt * 16 + lq * 4 + r;
            float bi = bo[o];
            float* dst = out + ((size_t)b * CC + o) * TT + tBase + wn * 64;
            #pragma unroll
            for (int nt = 0; nt < 4; nt++)
                dst[nt * 16 + l15] = acc[mt][nt][r] + bi;
        }
}

// ---------------------------------------------------------------------------
extern "C" void kernel_launch(void* const* d_in, const int* in_sizes, int n_in,
                              void* d_out, int out_size, void* d_ws, size_t ws_size,
                              hipStream_t stream)
{
    const float* x   = (const float*)d_in[0];
    const float* ctx = (const float*)d_in[1];
    const int* mask  = (const int*)d_in[2];
    const float* Wq  = (const float*)d_in[3];
    const float* bq  = (const float*)d_in[4];
    const float* Wk  = (const float*)d_in[5];
    const float* bk  = (const float*)d_in[6];
    const float* Wv  = (const float*)d_in[7];
    const float* bv  = (const float*)d_in[8];
    const float* Wo  = (const float*)d_in[9];
    const float* bo  = (const float*)d_in[10];
    float* out = (float*)d_out;

    const size_t nq = (size_t)BB * HH * TT * DD;        // 8M elems (16 MB bf16)
    const size_t nw = (size_t)CC * CC;                  // 1M elems

    if (ws_size >= (5 * nq + 4 * nw) * sizeof(unsigned short)) {
        // 88 MB: merged-qkv path (xT and ctxT both resident)
        unsigned short* q   = (unsigned short*)d_ws;    // [b,h,t,d] (pre-scaled)
        unsigned short* k   = q + nq;                   // [b,h,t,d]
        unsigned short* v   = k + nq;                   // [b,h,d,t]
        unsigned short* xT  = v + nq;                   // later reused as att
        unsigned short* cT  = xT + nq;
        unsigned short* Wb  = cT + nq;
        unsigned short* Wqb = Wb;
        unsigned short* Wkb = Wb + nw;
        unsigned short* Wvb = Wb + 2 * nw;
        unsigned short* Wob = Wb + 3 * nw;

        cast_w_kernel<<<dim3(1024, 4), 256, 0, stream>>>(Wq, Wk, Wv, Wo, Wb);
        tcast2_kernel<<<dim3(16, 16, BB * 2), 256, 0, stream>>>(x, ctx, xT, cT);
        qkv_gll_kernel<<<dim3(8, 8, BB * 3), 256, 0, stream>>>(
            xT, cT, Wqb, Wkb, Wvb, bq, bk, bv, q, k, v, 0);
        attn_mfma_kernel<<<dim3(BB * HH, TT / 64), 256, 0, stream>>>(
            q, k, v, mask, xT);
        oproj_gll_kernel<<<dim3(BB, 8, 8), 256, 0, stream>>>(xT, Wob, bo, out);
    } else if (ws_size >= (4 * nq + 4 * nw) * sizeof(unsigned short)) {
        // 72 MB: sequential-qkv path (buf reused xT -> ctxT -> att)
        unsigned short* q   = (unsigned short*)d_ws;
        unsigned short* k   = q + nq;
        unsigned short* v   = k + nq;
        unsigned short* buf = v + nq;
        unsigned short* Wb  = buf + nq;
        unsigned short* Wqb = Wb;
        unsigned short* Wkb = Wb + nw;
        unsigned short* Wvb = Wb + 2 * nw;
        unsigned short* Wob = Wb + 3 * nw;

        cast_w_kernel<<<dim3(1024, 4), 256, 0, stream>>>(Wq, Wk, Wv, Wo, Wb);
        tcast_kernel<<<dim3(16, 16, BB), 256, 0, stream>>>(x, buf);
        qkv_gll_kernel<<<dim3(8, 8, BB), 256, 0, stream>>>(
            buf, buf, Wqb, Wkb, Wvb, bq, bk, bv, q, k, v, 1);
        tcast_kernel<<<dim3(16, 16, BB), 256, 0, stream>>>(ctx, buf);
        qkv_gll_kernel<<<dim3(8, 8, BB * 2), 256, 0, stream>>>(
            buf, buf, Wqb, Wkb, Wvb, bq, bk, bv, q, k, v, 2);
        attn_mfma_kernel<<<dim3(BB * HH, TT / 64), 256, 0, stream>>>(
            q, k, v, mask, buf);
        oproj_gll_kernel<<<dim3(BB, 8, 8), 256, 0, stream>>>(buf, Wob, bo, out);
    } else {
        // 64 MB legacy fallback
        unsigned short* q   = (unsigned short*)d_ws;
        unsigned short* k   = q + nq;
        unsigned short* v   = k + nq;
        unsigned short* att = v + nq;
        qkv_mfma_kernel<<<dim3(8, 8, BB * 3), 256, 0, stream>>>(
            x, ctx, Wq, bq, Wk, bk, Wv, bv, q, k, v);
        attn_mfma_kernel<<<dim3(BB * HH, TT / 64), 256, 0, stream>>>(
            q, k, v, mask, att);
        oproj_mfma_kernel<<<dim3(8, 8, BB), 256, 0, stream>>>(att, Wo, bo, out);
    }
}